// Round 2
// 4634.045 us; speedup vs baseline: 1.1189x; 1.1189x over previous
//
#include <hip/hip_runtime.h>

// TopKActivationMLP: B=16384, IN=1024, H=2048, K=256, NC=1000
//   h0 = relu(topk256(x @ W0^T + b0))
//   h1 = relu(topk256(h0 @ W1^T + b1))
//   out = h1 @ Wc^T + bc
//
// R6 == R5 resubmit (R5 bench was an infra failure; no signal) with one
// defensive fix: topk round-0 candidate test no longer folds a shift-by-32
// (UB) — uses a running decided-bits mask instead.
// R5: (a) topk: 32-round 1-bit radix -> 4-round 8-bit LDS-histogram radix
// select (bit-identical threshold + same 64-bit tie path); (b) spmm: each
// lane gathers all 8 slab cols for its own row via 2x ds_read_b128 (8x fewer
// DS insts per work unit, near LDS BW floor for random k), 8 indep FMA
// chains, 4x fewer pv/pi loads. Value arithmetic order preserved exactly
// (fp64 layer0+1, p-ascending contracted FMA) -> selection bit-identical.

#define B_SZ 16384
#define IN_SZ 1024
#define H_SZ 2048
#define K_TOP 256
#define NC_SZ 1000
#define NC_PAD 1008  // 126 blocks of 8

// ---------- dense fp64 GEMM (layer 0): C = A @ Bt^T + bias --------------
__global__ __launch_bounds__(256, 4) void gemm_bt_v2(
    const float* __restrict__ A, const float* __restrict__ Bt,
    const float* __restrict__ bias, double* __restrict__ C,
    int M, int N, int Kd) {
  __shared__ double As[16][130];
  __shared__ double Bs[16][66];
  const int tid = threadIdx.x;
  const int tx = tid & 15;
  const int tym = tid >> 4;
  const int m0 = blockIdx.y * 128;
  const int n0 = blockIdx.x * 64;

  double acc[8][4];
#pragma unroll
  for (int i = 0; i < 8; ++i)
#pragma unroll
    for (int j = 0; j < 4; ++j) acc[i][j] = 0.0;

  for (int k0 = 0; k0 < Kd; k0 += 16) {
#pragma unroll
    for (int l = 0; l < 8; ++l) {
      const int idx = l * 256 + tid;
      const int rr = idx >> 4;
      const int kk = idx & 15;
      As[kk][rr] = (double)A[(size_t)(m0 + rr) * Kd + (k0 + kk)];
    }
#pragma unroll
    for (int l = 0; l < 4; ++l) {
      const int idx = l * 256 + tid;
      const int rr = idx >> 4;
      const int kk = idx & 15;
      Bs[kk][rr] = (double)Bt[(size_t)(n0 + rr) * Kd + (k0 + kk)];
    }
    __syncthreads();
#pragma unroll 4
    for (int kk = 0; kk < 16; ++kk) {
      double a[8], b[4];
#pragma unroll
      for (int i = 0; i < 8; ++i) a[i] = As[kk][tym + 16 * i];
#pragma unroll
      for (int j = 0; j < 4; ++j) b[j] = Bs[kk][tx + 16 * j];
#pragma unroll
      for (int i = 0; i < 8; ++i)
#pragma unroll
        for (int j = 0; j < 4; ++j) acc[i][j] = fma(a[i], b[j], acc[i][j]);
    }
    __syncthreads();
  }
#pragma unroll
  for (int i = 0; i < 8; ++i) {
    const int r = m0 + tym + 16 * i;
#pragma unroll
    for (int j = 0; j < 4; ++j) {
      const int c = n0 + tx + 16 * j;
      C[(size_t)r * N + c] = acc[i][j] + (double)bias[c];
    }
  }
}

__device__ __forceinline__ int blockReduceSum(int v, int* sred) {
#pragma unroll
  for (int o = 32; o > 0; o >>= 1) v += __shfl_down(v, o);
  const int tid = threadIdx.x;
  if ((tid & 63) == 0) sred[tid >> 6] = v;
  __syncthreads();
  int t = 0;
  if (tid < 4) t = sred[tid];
  t += __shfl_down(t, 2);
  t += __shfl_down(t, 1);
  if (tid == 0) sred[0] = t;
  __syncthreads();
  const int r = sred[0];
  __syncthreads();
  return r;
}

// ---------- top-k select + compact to exactly 256 (pv f64, pi idx) -------
// v2: 4-round 8-bit histogram radix select (bit-identical threshold to the
// old 32-round 1-bit radix; same rare-path 64-bit tie resolution).
__global__ __launch_bounds__(256) void topk_compact_v2(
    const double* __restrict__ h, double* __restrict__ pv,
    int* __restrict__ pi) {
  __shared__ int sred[4];
  __shared__ int hist[256];
  __shared__ int swsum[4];
  __shared__ unsigned int sprefix;
  __shared__ int srem;
  __shared__ int scnt;
  __shared__ unsigned long long ckey[128];
  __shared__ int cidx[128];
  __shared__ double sval[H_SZ];
  __shared__ unsigned char sflag[H_SZ];
  const int tid = threadIdx.x;
  const double* hr = h + (size_t)blockIdx.x * H_SZ;

  double myv[8];
  unsigned long long myk64[8];
  unsigned int myk[8];
#pragma unroll
  for (int l = 0; l < 8; ++l) {
    const int i = l * 256 + tid;
    const double v = hr[i];
    myv[l] = v;
    unsigned long long b = (unsigned long long)__double_as_longlong(v);
    unsigned long long u =
        (b & 0x8000000000000000ULL) ? ~b : (b | 0x8000000000000000ULL);
    myk64[l] = u;
    myk[l] = (unsigned int)(u >> 32);
  }

  // ---- 4-round histogram radix select on the high-32 key ----
  unsigned int prefix = 0;   // decided high bits
  unsigned int pmask = 0;    // mask of decided high bits (no UB shifts)
  int remaining = K_TOP;
#pragma unroll
  for (int round = 0; round < 4; ++round) {
    const int shift = 24 - 8 * round;
    hist[tid] = 0;  // own bin only; cross-thread use fenced below
    __syncthreads();
#pragma unroll
    for (int l = 0; l < 8; ++l) {
      const unsigned int u = myk[l];
      if ((u & pmask) == prefix) atomicAdd(&hist[(u >> shift) & 255], 1);
    }
    __syncthreads();
    const int v = hist[tid];  // thread tid owns bin tid
    // inclusive suffix-sum within 64-lane chunk
    int s = v;
#pragma unroll
    for (int off = 1; off < 64; off <<= 1) {
      const int t = __shfl_down(s, off);
      if ((tid & 63) + off < 64) s += t;
    }
    if ((tid & 63) == 0) swsum[tid >> 6] = s;
    __syncthreads();
    int S = s;
    for (int c = (tid >> 6) + 1; c < 4; ++c) S += swsum[c];
    // unique bucket: suffix crosses `remaining` here (only v>0 can match)
    if (S >= remaining && (S - v) < remaining) {
      sprefix = prefix | ((unsigned int)tid << shift);
      srem = remaining - (S - v);
    }
    __syncthreads();
    prefix = sprefix;
    remaining = srem;
    pmask |= (0xFFu << shift);
    __syncthreads();
  }

  const unsigned int T = prefix;
  const int need_eq = remaining;  // == K_TOP - count(key > T)

  int ce = 0;
#pragma unroll
  for (int l = 0; l < 8; ++l) ce += (myk[l] == T) ? 1 : 0;
  const int count_eq = blockReduceSum(ce, sred);

  bool keep[8];
#pragma unroll
  for (int l = 0; l < 8; ++l) keep[l] = (myk[l] > T);

  if (count_eq == need_eq) {
#pragma unroll
    for (int l = 0; l < 8; ++l) keep[l] = keep[l] || (myk[l] == T);
  } else {
    // rare: high-32 boundary collision -> exact 64-bit + index resolve
    if (tid == 0) scnt = 0;
    __syncthreads();
    int mypos[8];
#pragma unroll
    for (int l = 0; l < 8; ++l) mypos[l] = -1;
#pragma unroll
    for (int l = 0; l < 8; ++l) {
      if (myk[l] == T) {
        const int p = atomicAdd(&scnt, 1);
        if (p < 128) {
          ckey[p] = myk64[l];
          cidx[p] = l * 256 + tid;
          mypos[l] = p;
        }
      }
    }
    __syncthreads();
    const int c = (scnt < 128) ? scnt : 128;
#pragma unroll
    for (int l = 0; l < 8; ++l) {
      if (mypos[l] >= 0) {
        const unsigned long long k = ckey[mypos[l]];
        const int ii = cidx[mypos[l]];
        int rank = 0;
        for (int j = 0; j < c; ++j)
          rank += ((ckey[j] > k) || (ckey[j] == k && cidx[j] < ii)) ? 1 : 0;
        keep[l] = (rank < need_eq);
      }
    }
  }

#pragma unroll
  for (int l = 0; l < 8; ++l) {
    const int i = l * 256 + tid;
    sflag[i] = keep[l] ? 1 : 0;
    sval[i] = (keep[l] && myv[l] > 0.0) ? myv[l] : 0.0;
  }
  __syncthreads();

  // compact: thread t owns [8t, 8t+8); exclusive scan -> ascending index
  const int base_i = tid * 8;
  int cnt = 0;
  int pre[8];
#pragma unroll
  for (int j = 0; j < 8; ++j) {
    pre[j] = cnt;
    cnt += sflag[base_i + j];
  }
  int inc = cnt;
#pragma unroll
  for (int o = 1; o < 64; o <<= 1) {
    const int t = __shfl_up(inc, o);
    if ((tid & 63) >= o) inc += t;
  }
  if ((tid & 63) == 63) swsum[tid >> 6] = inc;
  __syncthreads();

  int wbase = 0;
  for (int w = 0; w < (tid >> 6); ++w) wbase += swsum[w];
  const int ebase = wbase + inc - cnt;

  double* pvr = pv + (size_t)blockIdx.x * K_TOP;
  int* pir = pi + (size_t)blockIdx.x * K_TOP;
#pragma unroll
  for (int j = 0; j < 8; ++j) {
    if (sflag[base_i + j]) {
      const int pos = ebase + pre[j];
      if (pos < K_TOP) {
        pvr[pos] = sval[base_i + j];
        pir[pos] = base_i + j;
      }
    }
  }
}

// ---------- pack W [N][K] -> blocked [cb][k][8], cb = n>>3 ---------------
__global__ __launch_bounds__(256) void pack_w_blocked(
    const float* __restrict__ in, float* __restrict__ out, int N, int Kd,
    int Npad) {
  __shared__ float t[32][33];
  const int bx = blockIdx.x * 32;  // k
  const int by = blockIdx.y * 32;  // n
#pragma unroll
  for (int s = 0; s < 32; s += 8) {
    const int n = by + threadIdx.y + s;
    const int k = bx + threadIdx.x;
    t[threadIdx.y + s][threadIdx.x] =
        (n < N && k < Kd) ? in[(size_t)n * Kd + k] : 0.f;
  }
  __syncthreads();
#pragma unroll
  for (int s = 0; s < 32; s += 8) {
    const int k = bx + threadIdx.y + s;
    const int n = by + threadIdx.x;
    if (k < Kd && n < Npad)
      out[(size_t)(n >> 3) * (Kd * 8) + (size_t)k * 8 + (n & 7)] =
          t[threadIdx.x][threadIdx.y + s];
  }
}

// ---------- fixed-trip SpMM over 8-col W slab (v2) -----------------------
// Wblk[cb]: [2048][8] fp32 staged in 64KB LDS. One lane = one row x all 8
// slab cols: per p, 2x ds_read_b128 gathers w[k][0..7] (near LDS BW floor
// for random k), 8 independent FMA chains. p ascending -> per-(row,col)
// accumulation order identical to v1 (bit-identical f64 layer-1 output).
template <typename ACC_T, typename OUT_T>
__global__ __launch_bounds__(256) void spmm8_v2(
    const double* __restrict__ pv, const int* __restrict__ pi,
    const float* __restrict__ Wblk, const float* __restrict__ bias,
    OUT_T* __restrict__ out, int rowsPerBlock, int Ncols, int strideN) {
  __shared__ float Ws[H_SZ * 8];  // 64 KB
  const int tid = threadIdx.x;
  const int cb = blockIdx.x;
  const float* src = Wblk + (size_t)cb * (H_SZ * 8);
#pragma unroll
  for (int i = 0; i < 16; ++i)
    ((float4*)Ws)[i * 256 + tid] = ((const float4*)src)[i * 256 + tid];
  __syncthreads();

  const int nb = cb * 8;
  ACC_T bs[8];
#pragma unroll
  for (int c = 0; c < 8; ++c)
    bs[c] = (nb + c < Ncols) ? (ACC_T)bias[nb + c] : (ACC_T)0;

  const int r0 = blockIdx.y * rowsPerBlock;
  for (int pass = 0; pass < rowsPerBlock / 256; ++pass) {
    const int r = r0 + pass * 256 + tid;
    const double* __restrict__ pvr = pv + (size_t)r * K_TOP;
    const int* __restrict__ pir = pi + (size_t)r * K_TOP;
    ACC_T a[8];
#pragma unroll
    for (int c = 0; c < 8; ++c) a[c] = (ACC_T)0;
#pragma unroll 8
    for (int p = 0; p < K_TOP; ++p) {
      const ACC_T v = (ACC_T)pvr[p];
      const int k = pir[p];
      const float4 w0 = *(const float4*)&Ws[k * 8];
      const float4 w1 = *(const float4*)&Ws[k * 8 + 4];
      a[0] += (ACC_T)w0.x * v;
      a[1] += (ACC_T)w0.y * v;
      a[2] += (ACC_T)w0.z * v;
      a[3] += (ACC_T)w0.w * v;
      a[4] += (ACC_T)w1.x * v;
      a[5] += (ACC_T)w1.y * v;
      a[6] += (ACC_T)w1.z * v;
      a[7] += (ACC_T)w1.w * v;
    }
    OUT_T* __restrict__ orow = out + (size_t)r * strideN + nb;
    if (nb + 7 < Ncols) {
#pragma unroll
      for (int c = 0; c < 8; ++c) orow[c] = (OUT_T)(a[c] + bs[c]);
    } else {
#pragma unroll
      for (int c = 0; c < 8; ++c)
        if (nb + c < Ncols) orow[c] = (OUT_T)(a[c] + bs[c]);
    }
  }
}

extern "C" void kernel_launch(void* const* d_in, const int* in_sizes, int n_in,
                              void* d_out, int out_size, void* d_ws, size_t ws_size,
                              hipStream_t stream) {
  const float* x  = (const float*)d_in[0];
  const float* W0 = (const float*)d_in[1];
  const float* b0 = (const float*)d_in[2];
  const float* W1 = (const float*)d_in[3];
  const float* b1 = (const float*)d_in[4];
  const float* Wc = (const float*)d_in[5];
  const float* bc = (const float*)d_in[6];
  float* out = (float*)d_out;

  auto align256 = [](size_t v) { return (v + 255) & ~(size_t)255; };
  char* base = (char*)d_ws;
  size_t off = 0;
  float* W1blk = (float*)(base + off);
  off = align256(off + (size_t)H_SZ * H_SZ * sizeof(float));       // 16.8 MB
  float* Wcblk = (float*)(base + off);
  off = align256(off + (size_t)H_SZ * NC_PAD * sizeof(float));     // 8.26 MB
  const size_t fixed = off;

  const size_t per_row =
      (size_t)H_SZ * 8 + K_TOP * 8 + K_TOP * 4;  // hd + pv + pi
  int chunkB = B_SZ;
  while (fixed + (size_t)chunkB * per_row + 4096 > ws_size && chunkB > 512)
    chunkB >>= 1;

  double* hd = (double*)(base + off);
  off = align256(off + (size_t)chunkB * H_SZ * sizeof(double));
  double* pv = (double*)(base + off);
  off = align256(off + (size_t)chunkB * K_TOP * sizeof(double));
  int* pi = (int*)(base + off);

  const dim3 blk(256);
  // one-time weight pack to blocked layout (coalesced LDS staging later)
  pack_w_blocked<<<dim3(H_SZ / 32, H_SZ / 32), dim3(32, 8), 0, stream>>>(
      W1, W1blk, H_SZ, H_SZ, H_SZ);
  pack_w_blocked<<<dim3(H_SZ / 32, (NC_PAD + 31) / 32), dim3(32, 8), 0,
                   stream>>>(Wc, Wcblk, NC_SZ, H_SZ, NC_PAD);

  const int RPB = 512;  // rows per spmm block (chunkB always divisible)
  for (int m0 = 0; m0 < B_SZ; m0 += chunkB) {
    const int M = chunkB;
    // layer 0: dense fp64
    gemm_bt_v2<<<dim3(H_SZ / 64, M / 128), blk, 0, stream>>>(
        x + (size_t)m0 * IN_SZ, W0, b0, hd, M, H_SZ, IN_SZ);
    topk_compact_v2<<<dim3(M), blk, 0, stream>>>(hd, pv, pi);
    // layer 1: f64-exact SpMM -> dense hd
    spmm8_v2<double, double><<<dim3(H_SZ / 8, M / RPB), blk, 0, stream>>>(
        pv, pi, W1blk, b1, hd, RPB, H_SZ, H_SZ);
    topk_compact_v2<<<dim3(M), blk, 0, stream>>>(hd, pv, pi);
    // layer 2: f32 SpMM -> output
    spmm8_v2<float, float><<<dim3(NC_PAD / 8, M / RPB), blk, 0, stream>>>(
        pv, pi, Wcblk, bc, out + (size_t)m0 * NC_SZ, RPB, NC_SZ, NC_SZ);
  }
}

// Round 4
// 3881.858 us; speedup vs baseline: 1.3357x; 1.1938x over previous
//
#include <hip/hip_runtime.h>

// TopKActivationMLP: B=16384, IN=1024, H=2048, K=256, NC=1000
//   h0 = relu(topk256(x @ W0^T + b0))
//   h1 = relu(topk256(h0 @ W1^T + b1))
//   out = h1 @ Wc^T + bc
//
// R8 == R7 resubmit (R7 bench: container failure, no kernel signal; R5
// precedent says infra) with one hardening change: the round-0 ballot
// aggregation loop is now a BOUNDED for-loop (<=64 iters, provable) with a
// plain-atomic fallback — a hypothetical miscompile now degrades to R6's
// atomic path instead of hanging the GPU.
// R7: (a) spmm v3: 1024-thread blocks (32 waves/CU vs 8 — DS unit was
// latency-starved at 2 waves/SIMD), packed+transposed pvk[rowblk64][p][lane]
// (one coalesced 16B dwordx4 per p, no L1 reliance); (b) topk round-0
// histogram via wave-aggregated ballot loop (fp64 high-byte keys concentrate
// in ~4 exponent bins -> 64-deep same-address LDS atomic serialization);
// (c) gemm split into 2x M=8192 dispatches for rocprof top-5 visibility.
// Value path bit-identical: same fp64 keys, same p-ascending FMA order.

#define B_SZ 16384
#define IN_SZ 1024
#define H_SZ 2048
#define K_TOP 256
#define NC_SZ 1000
#define NC_PAD 1008  // 126 blocks of 8

// ---------- dense fp64 GEMM (layer 0): C = A @ Bt^T + bias --------------
__global__ __launch_bounds__(256, 4) void gemm_bt_v2(
    const float* __restrict__ A, const float* __restrict__ Bt,
    const float* __restrict__ bias, double* __restrict__ C,
    int M, int N, int Kd) {
  __shared__ double As[16][130];
  __shared__ double Bs[16][66];
  const int tid = threadIdx.x;
  const int tx = tid & 15;
  const int tym = tid >> 4;
  const int m0 = blockIdx.y * 128;
  const int n0 = blockIdx.x * 64;

  double acc[8][4];
#pragma unroll
  for (int i = 0; i < 8; ++i)
#pragma unroll
    for (int j = 0; j < 4; ++j) acc[i][j] = 0.0;

  for (int k0 = 0; k0 < Kd; k0 += 16) {
#pragma unroll
    for (int l = 0; l < 8; ++l) {
      const int idx = l * 256 + tid;
      const int rr = idx >> 4;
      const int kk = idx & 15;
      As[kk][rr] = (double)A[(size_t)(m0 + rr) * Kd + (k0 + kk)];
    }
#pragma unroll
    for (int l = 0; l < 4; ++l) {
      const int idx = l * 256 + tid;
      const int rr = idx >> 4;
      const int kk = idx & 15;
      Bs[kk][rr] = (double)Bt[(size_t)(n0 + rr) * Kd + (k0 + kk)];
    }
    __syncthreads();
#pragma unroll 4
    for (int kk = 0; kk < 16; ++kk) {
      double a[8], b[4];
#pragma unroll
      for (int i = 0; i < 8; ++i) a[i] = As[kk][tym + 16 * i];
#pragma unroll
      for (int j = 0; j < 4; ++j) b[j] = Bs[kk][tx + 16 * j];
#pragma unroll
      for (int i = 0; i < 8; ++i)
#pragma unroll
        for (int j = 0; j < 4; ++j) acc[i][j] = fma(a[i], b[j], acc[i][j]);
    }
    __syncthreads();
  }
#pragma unroll
  for (int i = 0; i < 8; ++i) {
    const int r = m0 + tym + 16 * i;
#pragma unroll
    for (int j = 0; j < 4; ++j) {
      const int c = n0 + tx + 16 * j;
      C[(size_t)r * N + c] = acc[i][j] + (double)bias[c];
    }
  }
}

__device__ __forceinline__ int blockReduceSum(int v, int* sred) {
#pragma unroll
  for (int o = 32; o > 0; o >>= 1) v += __shfl_down(v, o);
  const int tid = threadIdx.x;
  if ((tid & 63) == 0) sred[tid >> 6] = v;
  __syncthreads();
  int t = 0;
  if (tid < 4) t = sred[tid];
  t += __shfl_down(t, 2);
  t += __shfl_down(t, 1);
  if (tid == 0) sred[0] = t;
  __syncthreads();
  const int r = sred[0];
  __syncthreads();
  return r;
}

// ---------- top-k select + compact to exactly 256 ------------------------
// Output: pvk transposed-packed: pvk[(row>>6)*256*64 + pos*64 + (row&63)]
//         = {key: f64 bits of relu'd value, idx}
// v3: round-0 histogram via wave-aggregated ballot (high-byte keys are
// exponent-concentrated -> same-bin atomics serialized 64-deep before).
// Bounded loop + fallback: provably terminating.
__global__ __launch_bounds__(256) void topk_compact_v3(
    const double* __restrict__ h, longlong2* __restrict__ pvk) {
  __shared__ int sred[4];
  __shared__ int hist[256];
  __shared__ int swsum[4];
  __shared__ unsigned int sprefix;
  __shared__ int srem;
  __shared__ int scnt;
  __shared__ unsigned long long ckey[128];
  __shared__ int cidx[128];
  __shared__ double sval[H_SZ];
  __shared__ unsigned char sflag[H_SZ];
  const int tid = threadIdx.x;
  const int row = blockIdx.x;
  const double* hr = h + (size_t)row * H_SZ;

  double myv[8];
  unsigned long long myk64[8];
  unsigned int myk[8];
#pragma unroll
  for (int l = 0; l < 8; ++l) {
    const int i = l * 256 + tid;
    const double v = hr[i];
    myv[l] = v;
    unsigned long long b = (unsigned long long)__double_as_longlong(v);
    unsigned long long u =
        (b & 0x8000000000000000ULL) ? ~b : (b | 0x8000000000000000ULL);
    myk64[l] = u;
    myk[l] = (unsigned int)(u >> 32);
  }

  // ---- 4-round histogram radix select on the high-32 key ----
  unsigned int prefix = 0;   // decided high bits
  unsigned int pmask = 0;    // mask of decided high bits
  int remaining = K_TOP;
#pragma unroll
  for (int round = 0; round < 4; ++round) {
    const int shift = 24 - 8 * round;
    hist[tid] = 0;
    __syncthreads();
    if (round == 0) {
      // wave-aggregated histogram: bins are exponent-concentrated, so the
      // distinct-bin count per wave is tiny; one atomic per distinct bin.
      // Bounded (each iter retires >=1 lane -> <=64 needed) + fallback.
#pragma unroll
      for (int l = 0; l < 8; ++l) {
        const int bin = (int)(myk[l] >> 24);
        bool pending = true;
        for (int it = 0; it < 64; ++it) {
          if (!__any(pending)) break;
          const unsigned long long m = __ballot(pending);
          const int src = (int)__ffsll(m) - 1;
          const int b = __shfl(bin, src);
          const bool mine = pending && (bin == b);
          const unsigned long long grp = __ballot(mine);
          if ((tid & 63) == src) atomicAdd(&hist[b], (int)__popcll(grp));
          if (mine) pending = false;
        }
        if (pending) atomicAdd(&hist[bin], 1);  // never in practice
      }
    } else {
#pragma unroll
      for (int l = 0; l < 8; ++l) {
        const unsigned int u = myk[l];
        if ((u & pmask) == prefix) atomicAdd(&hist[(u >> shift) & 255], 1);
      }
    }
    __syncthreads();
    const int v = hist[tid];  // thread tid owns bin tid
    // inclusive suffix-sum within 64-lane chunk
    int s = v;
#pragma unroll
    for (int off = 1; off < 64; off <<= 1) {
      const int t = __shfl_down(s, off);
      if ((tid & 63) + off < 64) s += t;
    }
    if ((tid & 63) == 0) swsum[tid >> 6] = s;
    __syncthreads();
    int S = s;
    for (int c = (tid >> 6) + 1; c < 4; ++c) S += swsum[c];
    // unique bucket: suffix crosses `remaining` here (only v>0 can match)
    if (S >= remaining && (S - v) < remaining) {
      sprefix = prefix | ((unsigned int)tid << shift);
      srem = remaining - (S - v);
    }
    __syncthreads();
    prefix = sprefix;
    remaining = srem;
    pmask |= (0xFFu << shift);
  }

  const unsigned int T = prefix;
  const int need_eq = remaining;  // == K_TOP - count(key > T)

  int ce = 0;
#pragma unroll
  for (int l = 0; l < 8; ++l) ce += (myk[l] == T) ? 1 : 0;
  const int count_eq = blockReduceSum(ce, sred);

  bool keep[8];
#pragma unroll
  for (int l = 0; l < 8; ++l) keep[l] = (myk[l] > T);

  if (count_eq == need_eq) {
#pragma unroll
    for (int l = 0; l < 8; ++l) keep[l] = keep[l] || (myk[l] == T);
  } else {
    // rare: high-32 boundary collision -> exact 64-bit + index resolve
    if (tid == 0) scnt = 0;
    __syncthreads();
    int mypos[8];
#pragma unroll
    for (int l = 0; l < 8; ++l) mypos[l] = -1;
#pragma unroll
    for (int l = 0; l < 8; ++l) {
      if (myk[l] == T) {
        const int p = atomicAdd(&scnt, 1);
        if (p < 128) {
          ckey[p] = myk64[l];
          cidx[p] = l * 256 + tid;
          mypos[l] = p;
        }
      }
    }
    __syncthreads();
    const int c = (scnt < 128) ? scnt : 128;
#pragma unroll
    for (int l = 0; l < 8; ++l) {
      if (mypos[l] >= 0) {
        const unsigned long long k = ckey[mypos[l]];
        const int ii = cidx[mypos[l]];
        int rank = 0;
        for (int j = 0; j < c; ++j)
          rank += ((ckey[j] > k) || (ckey[j] == k && cidx[j] < ii)) ? 1 : 0;
        keep[l] = (rank < need_eq);
      }
    }
  }

#pragma unroll
  for (int l = 0; l < 8; ++l) {
    const int i = l * 256 + tid;
    sflag[i] = keep[l] ? 1 : 0;
    sval[i] = (keep[l] && myv[l] > 0.0) ? myv[l] : 0.0;
  }
  __syncthreads();

  // compact: thread t owns [8t, 8t+8); exclusive scan -> ascending index
  const int base_i = tid * 8;
  int cnt = 0;
  int pre[8];
#pragma unroll
  for (int j = 0; j < 8; ++j) {
    pre[j] = cnt;
    cnt += sflag[base_i + j];
  }
  int inc = cnt;
#pragma unroll
  for (int o = 1; o < 64; o <<= 1) {
    const int t = __shfl_up(inc, o);
    if ((tid & 63) >= o) inc += t;
  }
  if ((tid & 63) == 63) swsum[tid >> 6] = inc;
  __syncthreads();

  int wbase = 0;
  for (int w = 0; w < (tid >> 6); ++w) wbase += swsum[w];
  const int ebase = wbase + inc - cnt;

  // transposed-packed output: [row>>6][pos][row&63]
  longlong2* __restrict__ po =
      pvk + ((size_t)(row >> 6) * K_TOP) * 64 + (row & 63);
#pragma unroll
  for (int j = 0; j < 8; ++j) {
    if (sflag[base_i + j]) {
      const int pos = ebase + pre[j];
      if (pos < K_TOP) {
        longlong2 e;
        e.x = __double_as_longlong(sval[base_i + j]);
        e.y = (long long)(base_i + j);
        po[(size_t)pos * 64] = e;
      }
    }
  }
}

// ---------- pack W [N][K] -> blocked [cb][k][8], cb = n>>3 ---------------
__global__ __launch_bounds__(256) void pack_w_blocked(
    const float* __restrict__ in, float* __restrict__ out, int N, int Kd,
    int Npad) {
  __shared__ float t[32][33];
  const int bx = blockIdx.x * 32;  // k
  const int by = blockIdx.y * 32;  // n
#pragma unroll
  for (int s = 0; s < 32; s += 8) {
    const int n = by + threadIdx.y + s;
    const int k = bx + threadIdx.x;
    t[threadIdx.y + s][threadIdx.x] =
        (n < N && k < Kd) ? in[(size_t)n * Kd + k] : 0.f;
  }
  __syncthreads();
#pragma unroll
  for (int s = 0; s < 32; s += 8) {
    const int k = bx + threadIdx.y + s;
    const int n = by + threadIdx.x;
    if (k < Kd && n < Npad)
      out[(size_t)(n >> 3) * (Kd * 8) + (size_t)k * 8 + (n & 7)] =
          t[threadIdx.x][threadIdx.y + s];
  }
}

// ---------- fixed-trip SpMM over 8-col W slab (v3) -----------------------
// 1024-thread blocks: 2 blocks/CU (64KB LDS each) = 32 waves/CU, 4x the TLP
// of v2 (DS unit was latency-starved at 2 waves/SIMD). pvk transposed:
// per p, wave reads 64 consecutive 16B entries (1KB coalesced, 1 inst).
// p ascending, same FMA order as v2 -> bit-identical outputs.
template <typename ACC_T, typename OUT_T>
__global__ __launch_bounds__(1024) void spmm8_v3(
    const longlong2* __restrict__ pvk, const float* __restrict__ Wblk,
    const float* __restrict__ bias, OUT_T* __restrict__ out, int Ncols,
    int strideN) {
  __shared__ float Ws[H_SZ * 8];  // 64 KB
  const int tid = threadIdx.x;
  const int cb = blockIdx.x;
  const float* src = Wblk + (size_t)cb * (H_SZ * 8);
#pragma unroll
  for (int i = 0; i < 4; ++i)
    ((float4*)Ws)[i * 1024 + tid] = ((const float4*)src)[i * 1024 + tid];
  __syncthreads();

  const int nb = cb * 8;
  const int r = blockIdx.y * 1024 + tid;
  const longlong2* __restrict__ pr =
      pvk + ((size_t)(r >> 6) * K_TOP) * 64 + (r & 63);

  ACC_T a[8];
#pragma unroll
  for (int c = 0; c < 8; ++c) a[c] = (ACC_T)0;
#pragma unroll 4
  for (int p = 0; p < K_TOP; ++p) {
    const longlong2 e = pr[(size_t)p * 64];
    const ACC_T v = (ACC_T)__longlong_as_double(e.x);
    const int k = (int)e.y;
    const float4 w0 = *(const float4*)&Ws[k * 8];
    const float4 w1 = *(const float4*)&Ws[k * 8 + 4];
    a[0] += (ACC_T)w0.x * v;
    a[1] += (ACC_T)w0.y * v;
    a[2] += (ACC_T)w0.z * v;
    a[3] += (ACC_T)w0.w * v;
    a[4] += (ACC_T)w1.x * v;
    a[5] += (ACC_T)w1.y * v;
    a[6] += (ACC_T)w1.z * v;
    a[7] += (ACC_T)w1.w * v;
  }
  OUT_T* __restrict__ orow = out + (size_t)r * strideN + nb;
  if (nb + 7 < Ncols) {
#pragma unroll
    for (int c = 0; c < 8; ++c) orow[c] = (OUT_T)(a[c] + (ACC_T)bias[nb + c]);
  } else {
#pragma unroll
    for (int c = 0; c < 8; ++c)
      if (nb + c < Ncols) orow[c] = (OUT_T)(a[c] + (ACC_T)bias[nb + c]);
  }
}

extern "C" void kernel_launch(void* const* d_in, const int* in_sizes, int n_in,
                              void* d_out, int out_size, void* d_ws, size_t ws_size,
                              hipStream_t stream) {
  const float* x  = (const float*)d_in[0];
  const float* W0 = (const float*)d_in[1];
  const float* b0 = (const float*)d_in[2];
  const float* W1 = (const float*)d_in[3];
  const float* b1 = (const float*)d_in[4];
  const float* Wc = (const float*)d_in[5];
  const float* bc = (const float*)d_in[6];
  float* out = (float*)d_out;

  auto align256 = [](size_t v) { return (v + 255) & ~(size_t)255; };
  char* base = (char*)d_ws;
  size_t off = 0;
  float* W1blk = (float*)(base + off);
  off = align256(off + (size_t)H_SZ * H_SZ * sizeof(float));       // 16.8 MB
  float* Wcblk = (float*)(base + off);
  off = align256(off + (size_t)H_SZ * NC_PAD * sizeof(float));     // 8.26 MB
  const size_t fixed = off;

  const size_t per_row =
      (size_t)H_SZ * 8 + (size_t)K_TOP * 16;  // hd + pvk
  int chunkB = B_SZ;
  while (fixed + (size_t)chunkB * per_row + 4096 > ws_size && chunkB > 1024)
    chunkB >>= 1;

  double* hd = (double*)(base + off);
  off = align256(off + (size_t)chunkB * H_SZ * sizeof(double));
  longlong2* pvk = (longlong2*)(base + off);

  const dim3 blk(256);
  // one-time weight pack to blocked layout (coalesced LDS staging later)
  pack_w_blocked<<<dim3(H_SZ / 32, H_SZ / 32), dim3(32, 8), 0, stream>>>(
      W1, W1blk, H_SZ, H_SZ, H_SZ);
  pack_w_blocked<<<dim3(H_SZ / 32, (NC_PAD + 31) / 32), dim3(32, 8), 0,
                   stream>>>(Wc, Wcblk, NC_SZ, H_SZ, NC_PAD);

  for (int m0 = 0; m0 < B_SZ; m0 += chunkB) {
    const int M = chunkB;
    // layer 0: dense fp64 (split in 2 for rocprof top-5 visibility)
    const int Mh = M / 2;
    gemm_bt_v2<<<dim3(H_SZ / 64, Mh / 128), blk, 0, stream>>>(
        x + (size_t)m0 * IN_SZ, W0, b0, hd, Mh, H_SZ, IN_SZ);
    gemm_bt_v2<<<dim3(H_SZ / 64, Mh / 128), blk, 0, stream>>>(
        x + (size_t)(m0 + Mh) * IN_SZ, W0, b0, hd + (size_t)Mh * H_SZ, Mh,
        H_SZ, IN_SZ);
    topk_compact_v3<<<dim3(M), blk, 0, stream>>>(hd, pvk);
    // layer 1: f64-exact SpMM -> dense hd
    spmm8_v3<double, double><<<dim3(H_SZ / 8, M / 1024), dim3(1024), 0,
                               stream>>>(pvk, W1blk, b1, hd, H_SZ, H_SZ);
    topk_compact_v3<<<dim3(M), blk, 0, stream>>>(hd, pvk);
    // layer 2: f32 SpMM -> output
    spmm8_v3<float, float><<<dim3(NC_PAD / 8, M / 1024), dim3(1024), 0,
                             stream>>>(pvk, Wcblk, bc,
                                       out + (size_t)m0 * NC_SZ, NC_SZ,
                                       NC_SZ);
  }
}